// Round 1
// baseline (383.075 us; speedup 1.0000x reference)
//
#include <hip/hip_runtime.h>
#include <stdint.h>
#include <math.h>

typedef __attribute__((ext_vector_type(8))) short bf16x8;
typedef __attribute__((ext_vector_type(4))) float f32x4;

#define TSEQ 4096
#define NBATCH 4
#define LOG2E 1.44269504088896340736f
#define SLOPE 0.70710678118654752440f

__device__ __forceinline__ unsigned short f32_to_bf16(float f) {
  union { float f; unsigned int u; } v; v.f = f;
  unsigned int r = v.u + 0x7fffu + ((v.u >> 16) & 1u);
  return (unsigned short)(r >> 16);
}

// ---------------- kernel 1: W (fp32) -> Wb (bf16), q rows pre-scaled by 1/32 ----
__global__ __launch_bounds__(256) void wconv_kernel(
    const float* __restrict__ wq, const float* __restrict__ wk,
    const float* __restrict__ wv, unsigned short* __restrict__ Wb) {
  int idx = blockIdx.x * 256 + threadIdx.x;  // 0 .. 192*1024-1
  int row = idx >> 10, col = idx & 1023;
  float v;
  if (row < 64)       v = wq[row * 1024 + col] * 0.03125f;  // fold C^-0.5 = 1/32 into Wq
  else if (row < 128) v = wk[(row - 64) * 1024 + col];
  else                v = wv[(row - 128) * 1024 + col];
  Wb[idx] = f32_to_bf16(v);
}

// ---------------- kernel 2: qkv projection via MFMA -----------------------------
// grid 256 x 256 threads; wave handles 16 rows x 192 cols, K=1024 in 32 steps.
__global__ __launch_bounds__(256) void proj_kernel(
    const float* __restrict__ x, const unsigned short* __restrict__ Wb,
    unsigned short* __restrict__ qb, unsigned short* __restrict__ kb,
    unsigned short* __restrict__ vt) {
  const int lane = threadIdx.x & 63;
  const int wave = threadIdx.x >> 6;
  const int l16 = lane & 15, quad = lane >> 4;
  const int r0 = blockIdx.x * 64 + wave * 16;  // flat row in [0, 16384)

  f32x4 acc[12];
#pragma unroll
  for (int i = 0; i < 12; ++i) acc[i] = (f32x4){0.f, 0.f, 0.f, 0.f};

  const float* xa = x + (size_t)(r0 + l16) * 1024 + quad * 8;
  const unsigned short* wb0 = Wb + (size_t)l16 * 1024 + quad * 8;

  for (int ks = 0; ks < 32; ++ks) {
    const f32x4* ap = (const f32x4*)(xa + ks * 32);
    f32x4 a0 = ap[0], a1 = ap[1];
    bf16x8 af;
#pragma unroll
    for (int j = 0; j < 4; ++j) af[j] = (short)f32_to_bf16(a0[j]);
#pragma unroll
    for (int j = 0; j < 4; ++j) af[4 + j] = (short)f32_to_bf16(a1[j]);

    bf16x8 bfr[12];
#pragma unroll
    for (int nt = 0; nt < 12; ++nt)
      bfr[nt] = *(const bf16x8*)(wb0 + (size_t)nt * 16384 + ks * 32);
#pragma unroll
    for (int nt = 0; nt < 12; ++nt)
      acc[nt] = __builtin_amdgcn_mfma_f32_16x16x32_bf16(af, bfr[nt], acc[nt], 0, 0, 0);
  }

  // epilogue: C/D layout col=lane&15, row=quad*4+reg (verified m89/m91)
#pragma unroll
  for (int nt = 0; nt < 12; ++nt) {
#pragma unroll
    for (int r = 0; r < 4; ++r) {
      int row = r0 + quad * 4 + r;  // flat row
      unsigned short hv = f32_to_bf16(acc[nt][r]);
      if (nt < 4) {
        qb[(size_t)row * 64 + nt * 16 + l16] = hv;
      } else if (nt < 8) {
        kb[(size_t)row * 64 + (nt - 4) * 16 + l16] = hv;
      } else {
        // V stored transposed: Vt[b][d][t]
        int b = row >> 12, t = row & 4095;
        vt[((size_t)b * 64 + (nt - 8) * 16 + l16) * TSEQ + t] = hv;
      }
    }
  }
}

// ---------------- kernel 3: causal flash attention with ALiBi -------------------
// 512 blocks x 128 threads (2 waves). Wave w of block i owns q-tile (w? 1023-i : i):
// per-block work is ~constant (rank i>>2 + rank (1023-i)>>2 ~ 255).
__global__ __launch_bounds__(128) void attn_kernel(
    const unsigned short* __restrict__ qb, const unsigned short* __restrict__ kb,
    const unsigned short* __restrict__ vt, float* __restrict__ out) {
  __shared__ unsigned short pbuf[2][16][88];  // stride 176 B: 16B-aligned, 2-way banks (free)

  const int lane = threadIdx.x & 63;
  const int wave = threadIdx.x >> 6;
  const int l16 = lane & 15, quad = lane >> 4;

  int tile = (wave == 0) ? (int)blockIdx.x : (1023 - (int)blockIdx.x);
  const int b = tile & 3;
  const int r0 = (tile >> 2) << 4;  // q-row base within batch

  const unsigned short* kbase = kb + (size_t)b * TSEQ * 64;
  const unsigned short* vbase = vt + (size_t)b * 64 * TSEQ;

  // Q A-frags (k=0..31, 32..63)
  const unsigned short* qrow = qb + ((size_t)(b * TSEQ + r0 + l16)) * 64 + quad * 8;
  bf16x8 qa0 = *(const bf16x8*)qrow;
  bf16x8 qa1 = *(const bf16x8*)(qrow + 32);

  f32x4 o[4];
#pragma unroll
  for (int dt = 0; dt < 4; ++dt) o[dt] = (f32x4){0.f, 0.f, 0.f, 0.f};
  float m[4], lsum[4];
#pragma unroll
  for (int r = 0; r < 4; ++r) { m[r] = -INFINITY; lsum[r] = 0.f; }

  const int ntiles = (r0 + 79) >> 6;
  for (int kt = 0; kt < ntiles; ++kt) {
    const int jb = kt << 6;
    int nvr = ((r0 - jb) >> 4) + 1;
    const int nv = nvr > 4 ? 4 : nvr;  // valid 16-key subtiles this tile

    float s[4][4];
    // ---- S = Q K^T (+ bias, causal mask) ----
#pragma unroll
    for (int nt = 0; nt < 4; ++nt) {
      if (nt >= nv) continue;
      const unsigned short* krow = kbase + (size_t)(jb + nt * 16 + l16) * 64 + quad * 8;
      f32x4 sa = (f32x4){0.f, 0.f, 0.f, 0.f};
      sa = __builtin_amdgcn_mfma_f32_16x16x32_bf16(qa0, *(const bf16x8*)krow, sa, 0, 0, 0);
      sa = __builtin_amdgcn_mfma_f32_16x16x32_bf16(qa1, *(const bf16x8*)(krow + 32), sa, 0, 0, 0);
      float bias = SLOPE * (float)(jb + nt * 16 + l16);  // +slope*j (row const cancels)
      bool diag = (jb + nt * 16) == r0;
#pragma unroll
      for (int r = 0; r < 4; ++r) {
        float sv = sa[r] + bias;
        if (diag && (l16 > quad * 4 + r)) sv = -INFINITY;
        s[nt][r] = sv;
      }
    }

    // ---- online softmax update ----
    float tmax[4];
#pragma unroll
    for (int r = 0; r < 4; ++r) {
      float t = s[0][r];
#pragma unroll
      for (int nt = 1; nt < 4; ++nt) if (nt < nv) t = fmaxf(t, s[nt][r]);
#pragma unroll
      for (int d = 1; d < 16; d <<= 1) t = fmaxf(t, __shfl_xor(t, d, 64));
      tmax[r] = t;
    }
    float al[4];
#pragma unroll
    for (int r = 0; r < 4; ++r) {
      float mn = fmaxf(m[r], tmax[r]);
      al[r] = exp2f((m[r] - mn) * LOG2E);
      m[r] = mn;
    }
    float rs[4] = {0.f, 0.f, 0.f, 0.f};
#pragma unroll
    for (int nt = 0; nt < 4; ++nt) {
      if (nt >= nv) continue;
#pragma unroll
      for (int r = 0; r < 4; ++r) {
        float p = exp2f((s[nt][r] - m[r]) * LOG2E);
        s[nt][r] = p;
        rs[r] += p;
      }
    }
#pragma unroll
    for (int r = 0; r < 4; ++r) {
#pragma unroll
      for (int d = 1; d < 16; d <<= 1) rs[r] += __shfl_xor(rs[r], d, 64);
      lsum[r] = lsum[r] * al[r] + rs[r];
    }
#pragma unroll
    for (int dt = 0; dt < 4; ++dt)
#pragma unroll
      for (int r = 0; r < 4; ++r) o[dt][r] *= al[r];

    // ---- P -> LDS (C-layout write), zero-fill invalid subtiles in covered ksteps ----
    const int lim = (nv > 2) ? 4 : 2;
#pragma unroll
    for (int nt = 0; nt < 4; ++nt) {
      if (nt >= lim) continue;
#pragma unroll
      for (int r = 0; r < 4; ++r) {
        unsigned short pv = (nt < nv) ? f32_to_bf16(s[nt][r]) : (unsigned short)0;
        pbuf[wave][quad * 4 + r][nt * 16 + l16] = pv;
      }
    }
    // A-frags of P (same-wave LDS RAW: HW DS pipe is in-order, compiler inserts lgkmcnt)
    bf16x8 pa0 = *(const bf16x8*)&pbuf[wave][l16][quad * 8];
    bf16x8 pa1;
    if (nv > 2) pa1 = *(const bf16x8*)&pbuf[wave][l16][32 + quad * 8];

    // ---- O += P V ----
#pragma unroll
    for (int dt = 0; dt < 4; ++dt) {
      const unsigned short* vrow = vbase + (size_t)(dt * 16 + l16) * TSEQ + jb + quad * 8;
      o[dt] = __builtin_amdgcn_mfma_f32_16x16x32_bf16(pa0, *(const bf16x8*)vrow, o[dt], 0, 0, 0);
      if (nv > 2)
        o[dt] = __builtin_amdgcn_mfma_f32_16x16x32_bf16(pa1, *(const bf16x8*)(vrow + 32), o[dt], 0, 0, 0);
    }
  }

  // ---- epilogue: out = O / l ----
  float inv[4];
#pragma unroll
  for (int r = 0; r < 4; ++r) inv[r] = 1.0f / lsum[r];
  float* ob = out + ((size_t)(b * TSEQ + r0)) * 64;
#pragma unroll
  for (int dt = 0; dt < 4; ++dt)
#pragma unroll
    for (int r = 0; r < 4; ++r)
      ob[(size_t)(quad * 4 + r) * 64 + dt * 16 + l16] = o[dt][r] * inv[r];
}

extern "C" void kernel_launch(void* const* d_in, const int* in_sizes, int n_in,
                              void* d_out, int out_size, void* d_ws, size_t ws_size,
                              hipStream_t stream) {
  const float* x  = (const float*)d_in[0];
  const float* wq = (const float*)d_in[1];
  const float* wk = (const float*)d_in[2];
  const float* wv = (const float*)d_in[3];
  float* out = (float*)d_out;

  // workspace layout (bytes): Wb 384K | qb 2M | kb 2M | vt 2M  (~6.4 MB total)
  char* ws = (char*)d_ws;
  unsigned short* Wb = (unsigned short*)(ws);
  unsigned short* qb = (unsigned short*)(ws + 393216);
  unsigned short* kb = (unsigned short*)(ws + 393216 + 2097152);
  unsigned short* vt = (unsigned short*)(ws + 393216 + 2 * 2097152);

  wconv_kernel<<<768, 256, 0, stream>>>(wq, wk, wv, Wb);
  proj_kernel<<<256, 256, 0, stream>>>(x, Wb, qb, kb, vt);
  attn_kernel<<<512, 128, 0, stream>>>(qb, kb, vt, out);
}

// Round 2
// 162.942 us; speedup vs baseline: 2.3510x; 2.3510x over previous
//
#include <hip/hip_runtime.h>
#include <stdint.h>
#include <math.h>

typedef __attribute__((ext_vector_type(8))) short bf16x8;
typedef __attribute__((ext_vector_type(4))) float f32x4;

#define TSEQ 4096
#define LOG2E 1.44269504088896340736f
#define SLOPE 0.70710678118654752440f
#define SL2E (SLOPE * LOG2E)

__device__ __forceinline__ unsigned short f32_to_bf16(float f) {
  union { float f; unsigned int u; } v; v.f = f;
  unsigned int r = v.u + 0x7fffu + ((v.u >> 16) & 1u);
  return (unsigned short)(r >> 16);
}

// ---- kernel 1: W fp32 -> bf16 (q pre-scaled by 1/32) + fill vt "ones" rows ----
__global__ __launch_bounds__(256) void wconv_kernel(
    const float* __restrict__ wq, const float* __restrict__ wk,
    const float* __restrict__ wv, unsigned short* __restrict__ Wb,
    unsigned short* __restrict__ vt) {
  int idx = blockIdx.x * 256 + threadIdx.x;  // 0 .. 262143
  if (idx < 196608) {
    int row = idx >> 10, col = idx & 1023;
    float v;
    if (row < 64)       v = wq[row * 1024 + col] * 0.03125f;
    else if (row < 128) v = wk[(row - 64) * 1024 + col];
    else                v = wv[(row - 128) * 1024 + col];
    Wb[idx] = f32_to_bf16(v);
  }
  // vt dims 64..79 = 1.0 (row-sum trick): vt layout [4][80][4096]
  int b = idx >> 16, off = idx & 65535;
  vt[(size_t)b * 327680 + 262144 + off] = 0x3F80;  // bf16 1.0
}

// ---- kernel 2: qkv projection; wave = (16 rows) x (one of q/k/v, 64 cols) ----
__global__ __launch_bounds__(256) void proj_kernel(
    const float* __restrict__ x, const unsigned short* __restrict__ Wb,
    unsigned short* __restrict__ qb, unsigned short* __restrict__ kb,
    unsigned short* __restrict__ vt) {
  const int lane = threadIdx.x & 63;
  const int wave = threadIdx.x >> 6;
  const int l16 = lane & 15, quad = lane >> 4;
  const int id = blockIdx.x * 4 + wave;  // 0..3071
  const int rg = id / 3;                 // row-group 0..1023 (3 adjacent waves share rg -> L1 reuse of x)
  const int t = id - rg * 3;             // 0=q 1=k 2=v
  const int r0 = rg << 4;                // flat row base in [0,16384)

  f32x4 acc[4];
#pragma unroll
  for (int i = 0; i < 4; ++i) acc[i] = (f32x4){0.f, 0.f, 0.f, 0.f};

  const float* xa = x + (size_t)(r0 + l16) * 1024 + quad * 8;
  const unsigned short* wb0 = Wb + ((size_t)t * 64 + l16) * 1024 + quad * 8;

  for (int ks = 0; ks < 32; ++ks) {
    const f32x4* ap = (const f32x4*)(xa + ks * 32);
    f32x4 a0 = ap[0], a1 = ap[1];
    bf16x8 af;
#pragma unroll
    for (int j = 0; j < 4; ++j) af[j] = (short)f32_to_bf16(a0[j]);
#pragma unroll
    for (int j = 0; j < 4; ++j) af[4 + j] = (short)f32_to_bf16(a1[j]);
    bf16x8 bfr[4];
#pragma unroll
    for (int nt = 0; nt < 4; ++nt)
      bfr[nt] = *(const bf16x8*)(wb0 + (size_t)(nt * 16) * 1024 + ks * 32);
#pragma unroll
    for (int nt = 0; nt < 4; ++nt)
      acc[nt] = __builtin_amdgcn_mfma_f32_16x16x32_bf16(af, bfr[nt], acc[nt], 0, 0, 0);
  }

#pragma unroll
  for (int nt = 0; nt < 4; ++nt) {
#pragma unroll
    for (int r = 0; r < 4; ++r) {
      int row = r0 + quad * 4 + r;
      unsigned short hv = f32_to_bf16(acc[nt][r]);
      if (t == 0) {
        qb[(size_t)row * 64 + nt * 16 + l16] = hv;
      } else if (t == 1) {
        kb[(size_t)row * 64 + nt * 16 + l16] = hv;
      } else {
        int b = row >> 12, tt = row & 4095;
        vt[((size_t)b * 80 + nt * 16 + l16) * TSEQ + tt] = hv;
      }
    }
  }
}

// ---- kernel 3: windowed causal attention (ALiBi window=128 keys, exact to 1e-34) ----
// wave = one 16-row q-tile; 2 k-tiles of 64 keys ending at the diagonal.
// m-hat = slope*row analytic (no max reduce); l via ones-rows of V (no sum reduce).
__global__ __launch_bounds__(256) void attn_kernel(
    const unsigned short* __restrict__ qb, const unsigned short* __restrict__ kb,
    const unsigned short* __restrict__ vt, float* __restrict__ out) {
  __shared__ unsigned short pbuf[4][16][88];  // per-wave P tile; stride 176B (<=2-way banks, free)

  const int lane = threadIdx.x & 63;
  const int wave = threadIdx.x >> 6;
  const int l16 = lane & 15, quad = lane >> 4;
  const int id = blockIdx.x * 4 + wave;  // 0..1023
  const int b = id & 3;
  const int r0 = (id >> 2) << 4;
  const int j0 = (r0 > 112) ? (r0 - 112) : 0;

  const unsigned short* kbase = kb + (size_t)b * TSEQ * 64;
  const unsigned short* vbase = vt + (size_t)b * 80 * TSEQ;

  const unsigned short* qrow = qb + (size_t)(b * TSEQ + r0 + l16) * 64 + quad * 8;
  bf16x8 qa0 = *(const bf16x8*)qrow;
  bf16x8 qa1 = *(const bf16x8*)(qrow + 32);

  f32x4 o[5];
#pragma unroll
  for (int dt = 0; dt < 5; ++dt) o[dt] = (f32x4){0.f, 0.f, 0.f, 0.f};

  const int irel = j0 + l16 - r0 - quad * 4;  // (j - row) at kt=0,nt=0,r=0
  const float fb = SL2E * (float)irel;

#pragma unroll
  for (int kt = 0; kt < 2; ++kt) {
    const int jb = j0 + kt * 64;
    const bool needmask = (kt == 1) || (r0 < 64);

#pragma unroll
    for (int nt = 0; nt < 4; ++nt) {
      const unsigned short* krow = kbase + (size_t)(jb + nt * 16 + l16) * 64 + quad * 8;
      f32x4 sa = (f32x4){0.f, 0.f, 0.f, 0.f};
      sa = __builtin_amdgcn_mfma_f32_16x16x32_bf16(qa0, *(const bf16x8*)krow, sa, 0, 0, 0);
      sa = __builtin_amdgcn_mfma_f32_16x16x32_bf16(qa1, *(const bf16x8*)(krow + 32), sa, 0, 0, 0);
      const int koff = kt * 64 + nt * 16;
#pragma unroll
      for (int r = 0; r < 4; ++r) {
        float arg = fmaf(sa[r], LOG2E, fb + SL2E * (float)(koff - r));
        float p = exp2f(arg);
        if (needmask && (irel + koff - r > 0)) p = 0.f;  // causal
        pbuf[wave][quad * 4 + r][nt * 16 + l16] = f32_to_bf16(p);
      }
    }
    // same-wave DS pipe is in-order: write->read safe (validated in R1)
    bf16x8 pa0 = *(const bf16x8*)&pbuf[wave][l16][quad * 8];
    bf16x8 pa1 = *(const bf16x8*)&pbuf[wave][l16][32 + quad * 8];

#pragma unroll
    for (int dt = 0; dt < 5; ++dt) {  // dt=4 is the ones-tile: accumulates l = sum(p)
      const unsigned short* vrow = vbase + (size_t)(dt * 16 + l16) * TSEQ + jb + quad * 8;
      o[dt] = __builtin_amdgcn_mfma_f32_16x16x32_bf16(pa0, *(const bf16x8*)vrow, o[dt], 0, 0, 0);
      o[dt] = __builtin_amdgcn_mfma_f32_16x16x32_bf16(pa1, *(const bf16x8*)(vrow + 32), o[dt], 0, 0, 0);
    }
  }

  float inv[4];
#pragma unroll
  for (int r = 0; r < 4; ++r) inv[r] = 1.0f / o[4][r];
  float* ob = out + (size_t)(b * TSEQ + r0) * 64;
#pragma unroll
  for (int dt = 0; dt < 4; ++dt)
#pragma unroll
    for (int r = 0; r < 4; ++r)
      ob[(size_t)(quad * 4 + r) * 64 + dt * 16 + l16] = o[dt][r] * inv[r];
}

extern "C" void kernel_launch(void* const* d_in, const int* in_sizes, int n_in,
                              void* d_out, int out_size, void* d_ws, size_t ws_size,
                              hipStream_t stream) {
  const float* x  = (const float*)d_in[0];
  const float* wq = (const float*)d_in[1];
  const float* wk = (const float*)d_in[2];
  const float* wv = (const float*)d_in[3];
  float* out = (float*)d_out;

  // ws layout (bytes): Wb 384K | qb 2M | kb 2M | vt 2.62M (80 rows: 64 V + 16 ones)
  char* ws = (char*)d_ws;
  unsigned short* Wb = (unsigned short*)(ws);
  unsigned short* qb = (unsigned short*)(ws + 393216);
  unsigned short* kb = (unsigned short*)(ws + 393216 + 2097152);
  unsigned short* vt = (unsigned short*)(ws + 393216 + 2 * 2097152);

  wconv_kernel<<<1024, 256, 0, stream>>>(wq, wk, wv, Wb, vt);
  proj_kernel<<<768, 256, 0, stream>>>(x, Wb, qb, kb, vt);
  attn_kernel<<<256, 256, 0, stream>>>(qb, kb, vt, out);
}

// Round 3
// 145.961 us; speedup vs baseline: 2.6245x; 1.1163x over previous
//
#include <hip/hip_runtime.h>
#include <stdint.h>
#include <math.h>

typedef __attribute__((ext_vector_type(8))) short bf16x8;
typedef __attribute__((ext_vector_type(4))) float f32x4;

#define TSEQ 4096
#define LOG2E 1.44269504088896340736f
#define SLOPE 0.70710678118654752440f
#define SL2E (SLOPE * LOG2E)

__device__ __forceinline__ unsigned short f32_to_bf16(float f) {
  union { float f; unsigned int u; } v; v.f = f;
  unsigned int r = v.u + 0x7fffu + ((v.u >> 16) & 1u);
  return (unsigned short)(r >> 16);
}

// async global->LDS, 16B per lane; LDS dest = wave-uniform base + lane*16 (m104/m108)
__device__ __forceinline__ void async_cp16(const float* g, float* l) {
  __builtin_amdgcn_global_load_lds(
      (const __attribute__((address_space(1))) unsigned int*)g,
      (__attribute__((address_space(3))) unsigned int*)l, 16, 0, 0);
}

// ---- kernel 1: W fp32 -> bf16 (q pre-scaled by 1/32) + fill vt "ones" rows ----
__global__ __launch_bounds__(256) void wconv_kernel(
    const float* __restrict__ wq, const float* __restrict__ wk,
    const float* __restrict__ wv, unsigned short* __restrict__ Wb,
    unsigned short* __restrict__ vt) {
  int idx = blockIdx.x * 256 + threadIdx.x;  // 0 .. 262143
  if (idx < 196608) {
    int row = idx >> 10, col = idx & 1023;
    float v;
    if (row < 64)       v = wq[row * 1024 + col] * 0.03125f;
    else if (row < 128) v = wk[(row - 64) * 1024 + col];
    else                v = wv[(row - 128) * 1024 + col];
    Wb[idx] = f32_to_bf16(v);
  }
  // vt dims 64..79 = 1.0 (row-sum trick): vt layout [4][80][4096]
  int b = idx >> 16, off = idx & 65535;
  vt[(size_t)b * 327680 + 262144 + off] = 0x3F80;  // bf16 1.0
}

// ---- kernel 2: qkv projection, LDS-staged (m97 pattern) ------------------------
// 512 blocks x 256 threads. Block: 32 rows x 192 cols, K=1024 in 16 steps of 64.
// x tile staged via global_load_lds; 16B-slot XOR swizzle keeps ds_read_b128 at
// 2 lanes/bank (free) while staging stays coalesced.
__global__ __launch_bounds__(256) void proj_kernel(
    const float* __restrict__ x, const unsigned short* __restrict__ Wb,
    unsigned short* __restrict__ qb, unsigned short* __restrict__ kb,
    unsigned short* __restrict__ vt) {
  __shared__ float xbuf[32][64];  // 8 KB; row r slot p16 holds global chunk p16^(r&15)

  const int lane = threadIdx.x & 63;
  const int wave = threadIdx.x >> 6;
  const int l16 = lane & 15, quad = lane >> 4;
  const int s = wave >> 1;  // row strip (16 rows)
  const int h = wave & 1;   // col half (6 coltiles of 16)
  const int R0 = blockIdx.x * 32;

  f32x4 acc[6];
#pragma unroll
  for (int i = 0; i < 6; ++i) acc[i] = (f32x4){0.f, 0.f, 0.f, 0.f};

  // staging: wave stages chunks {2w, 2w+1}; chunk c = 4 rows (c*4..c*4+3) x 256B
  const int rA = wave * 8 + (lane >> 4);
  const int rB = rA + 4;
  const int gA = (lane & 15) ^ (rA & 15);
  const int gB = (lane & 15) ^ (rB & 15);
  const float* srcA = x + (size_t)(R0 + rA) * 1024 + gA * 4;
  const float* srcB = x + (size_t)(R0 + rB) * 1024 + gB * 4;
  float* dstA = &xbuf[wave * 8][0];
  float* dstB = &xbuf[wave * 8 + 4][0];

  // A-frag read pointers: row = s*16+l16, global 16B chunk g16 = ss*8+quad*2+pp,
  // swizzled slot = g16 ^ l16  (row&15 == l16 since strips start at 0/16)
  const float* ard[2][2];
#pragma unroll
  for (int ss = 0; ss < 2; ++ss)
#pragma unroll
    for (int pp = 0; pp < 2; ++pp)
      ard[ss][pp] = &xbuf[s * 16 + l16][((ss * 8 + quad * 2 + pp) ^ l16) * 4];

  const unsigned short* wb0 = Wb + (size_t)(h * 96 + l16) * 1024 + quad * 8;

  for (int step = 0; step < 16; ++step) {
    const int k0 = step * 64;
    async_cp16(srcA + k0, dstA);
    async_cp16(srcB + k0, dstB);
    __syncthreads();  // vmcnt drain + barrier: tile ready

#pragma unroll
    for (int ss = 0; ss < 2; ++ss) {
      f32x4 a0 = *(const f32x4*)ard[ss][0];
      f32x4 a1 = *(const f32x4*)ard[ss][1];
      bf16x8 af;
#pragma unroll
      for (int j = 0; j < 4; ++j) af[j] = (short)f32_to_bf16(a0[j]);
#pragma unroll
      for (int j = 0; j < 4; ++j) af[4 + j] = (short)f32_to_bf16(a1[j]);
      const unsigned short* wp = wb0 + k0 + ss * 32;
#pragma unroll
      for (int j = 0; j < 6; ++j) {
        bf16x8 bfr = *(const bf16x8*)(wp + (size_t)j * 16384);
        acc[j] = __builtin_amdgcn_mfma_f32_16x16x32_bf16(af, bfr, acc[j], 0, 0, 0);
      }
    }
    __syncthreads();  // protect tile before next overwrite
  }

  // epilogue: C/D col=l16, row=quad*4+r
#pragma unroll
  for (int j = 0; j < 6; ++j) {
    const int ci = h * 6 + j;  // global coltile 0..11
#pragma unroll
    for (int r = 0; r < 4; ++r) {
      int row = R0 + s * 16 + quad * 4 + r;
      unsigned short hv = f32_to_bf16(acc[j][r]);
      if (ci < 4) {
        qb[(size_t)row * 64 + ci * 16 + l16] = hv;
      } else if (ci < 8) {
        kb[(size_t)row * 64 + (ci - 4) * 16 + l16] = hv;
      } else {
        int b = row >> 12, tt = row & 4095;
        vt[((size_t)b * 80 + (ci - 8) * 16 + l16) * TSEQ + tt] = hv;
      }
    }
  }
}

// ---- kernel 3: windowed causal attention, 2 waves per q-tile -------------------
// Analytic shift (slope*row) makes partials linear: O = O_a + O_b, l = l_a + l_b.
// 512 blocks x 4 waves; wave = (q-tile, key-half of 64). Combine via LDS.
__global__ __launch_bounds__(256) void attn_kernel(
    const unsigned short* __restrict__ qb, const unsigned short* __restrict__ kb,
    const unsigned short* __restrict__ vt, float* __restrict__ out) {
  __shared__ unsigned short pbuf[4][16][88];  // P tiles (2-way banks, free)
  __shared__ float obuf[4][5][16][17];        // partial O (+l in [4])

  const int lane = threadIdx.x & 63;
  const int wave = threadIdx.x >> 6;
  const int l16 = lane & 15, quad = lane >> 4;
  const int qi = wave >> 1;  // block's q-tile 0/1
  const int h = wave & 1;    // key half
  const int tid = blockIdx.x * 2 + qi;  // 0..1023
  const int b = tid & 3;
  const int r0 = (tid >> 2) << 4;
  const int j0 = (r0 > 112) ? (r0 - 112) : 0;
  const int jb = j0 + h * 64;

  const unsigned short* kbase = kb + (size_t)b * TSEQ * 64;
  const unsigned short* vbase = vt + (size_t)b * 80 * TSEQ;

  const unsigned short* qrow = qb + (size_t)(b * TSEQ + r0 + l16) * 64 + quad * 8;
  bf16x8 qa0 = *(const bf16x8*)qrow;
  bf16x8 qa1 = *(const bf16x8*)(qrow + 32);

  f32x4 o[5];
#pragma unroll
  for (int dt = 0; dt < 5; ++dt) o[dt] = (f32x4){0.f, 0.f, 0.f, 0.f};

  const int irel = jb + l16 - r0 - quad * 4;  // j - row at nt=0,r=0
  const float fb = SL2E * (float)irel;
  const bool needmask = (h == 1) || (r0 < 64);

#pragma unroll
  for (int nt = 0; nt < 4; ++nt) {
    const unsigned short* krow = kbase + (size_t)(jb + nt * 16 + l16) * 64 + quad * 8;
    f32x4 sa = (f32x4){0.f, 0.f, 0.f, 0.f};
    sa = __builtin_amdgcn_mfma_f32_16x16x32_bf16(qa0, *(const bf16x8*)krow, sa, 0, 0, 0);
    sa = __builtin_amdgcn_mfma_f32_16x16x32_bf16(qa1, *(const bf16x8*)(krow + 32), sa, 0, 0, 0);
    const int koff = nt * 16;
#pragma unroll
    for (int r = 0; r < 4; ++r) {
      float arg = fmaf(sa[r], LOG2E, fb + SL2E * (float)(koff - r));
      float p = exp2f(arg);
      if (needmask && (irel + koff - r > 0)) p = 0.f;  // causal
      pbuf[wave][quad * 4 + r][nt * 16 + l16] = f32_to_bf16(p);
    }
  }
  // same-wave DS write->read is in-order (validated R1/R2)
  bf16x8 pa0 = *(const bf16x8*)&pbuf[wave][l16][quad * 8];
  bf16x8 pa1 = *(const bf16x8*)&pbuf[wave][l16][32 + quad * 8];

#pragma unroll
  for (int dt = 0; dt < 5; ++dt) {  // dt=4: ones rows -> l = sum(p)
    const unsigned short* vrow = vbase + (size_t)(dt * 16 + l16) * TSEQ + jb + quad * 8;
    o[dt] = __builtin_amdgcn_mfma_f32_16x16x32_bf16(pa0, *(const bf16x8*)vrow, o[dt], 0, 0, 0);
    o[dt] = __builtin_amdgcn_mfma_f32_16x16x32_bf16(pa1, *(const bf16x8*)(vrow + 32), o[dt], 0, 0, 0);
  }

#pragma unroll
  for (int dt = 0; dt < 5; ++dt)
#pragma unroll
    for (int r = 0; r < 4; ++r)
      obuf[wave][dt][quad * 4 + r][l16] = o[dt][r];

  __syncthreads();

  // combine: 2048 outputs, 8 per thread
  const int qt = threadIdx.x >> 7;
  const int rr = (threadIdx.x >> 3) & 15;
  const int c0 = (threadIdx.x & 7) * 8;
  const int tid2 = blockIdx.x * 2 + qt;
  const int b2 = tid2 & 3;
  const int r02 = (tid2 >> 2) << 4;
  float l = obuf[qt * 2][4][rr][0] + obuf[qt * 2 + 1][4][rr][0];
  float invl = 1.0f / l;
  float res[8];
#pragma unroll
  for (int i = 0; i < 8; ++i) {
    int c = c0 + i;
    res[i] = (obuf[qt * 2][c >> 4][rr][c & 15] + obuf[qt * 2 + 1][c >> 4][rr][c & 15]) * invl;
  }
  float* ob = out + (size_t)(b2 * TSEQ + r02 + rr) * 64 + c0;
  *(f32x4*)ob = (f32x4){res[0], res[1], res[2], res[3]};
  *(f32x4*)(ob + 4) = (f32x4){res[4], res[5], res[6], res[7]};
}

extern "C" void kernel_launch(void* const* d_in, const int* in_sizes, int n_in,
                              void* d_out, int out_size, void* d_ws, size_t ws_size,
                              hipStream_t stream) {
  const float* x  = (const float*)d_in[0];
  const float* wq = (const float*)d_in[1];
  const float* wk = (const float*)d_in[2];
  const float* wv = (const float*)d_in[3];
  float* out = (float*)d_out;

  // ws layout (bytes): Wb 384K | qb 2M | kb 2M | vt 2.62M (80 rows: 64 V + 16 ones)
  char* ws = (char*)d_ws;
  unsigned short* Wb = (unsigned short*)(ws);
  unsigned short* qb = (unsigned short*)(ws + 393216);
  unsigned short* kb = (unsigned short*)(ws + 393216 + 2097152);
  unsigned short* vt = (unsigned short*)(ws + 393216 + 2 * 2097152);

  wconv_kernel<<<1024, 256, 0, stream>>>(wq, wk, wv, Wb, vt);
  proj_kernel<<<512, 256, 0, stream>>>(x, Wb, qb, kb, vt);
  attn_kernel<<<512, 256, 0, stream>>>(qb, kb, vt, out);
}